// Round 5
// baseline (1647.424 us; speedup 1.0000x reference)
//
#include <hip/hip_runtime.h>
#include <math.h>

#define HID    1024
#define GG     64
#define KPROP  5
#define H1     512
#define H2     256
#define NCLS   40
#define BNEPS  1e-5f
#define TILE   2048
#define BPART  256     // partition blocks
#define NBINS  1024    // buckets of 128 nodes (supports n <= 131072)
#define LDSCAP 8192    // max edges per bucket staged in LDS (mean ~4096, sd ~64)

__host__ __device__ static inline int cdiv(int a, int b) { return (a + b - 1) / b; }

// ---------- Pass A: per-block histogram of col>>7 ----------
__global__ __launch_bounds__(1024) void k_hista(const int* __restrict__ col,
                                                int* __restrict__ blockHist, int e) {
    __shared__ int h[NBINS];
    for (int i = threadIdx.x; i < NBINS; i += 1024) h[i] = 0;
    __syncthreads();
    int chunk = cdiv(e, gridDim.x);
    int s = blockIdx.x * chunk, t = min(e, s + chunk);
    for (int i = s + threadIdx.x; i < t; i += 1024) atomicAdd(&h[col[i] >> 7], 1);
    __syncthreads();
    for (int i = threadIdx.x; i < NBINS; i += 1024)
        blockHist[blockIdx.x * NBINS + i] = h[i];
}

// ---------- Pass B: per-(block,bucket) exclusive offsets + bucket starts ----------
__global__ __launch_bounds__(1024) void k_scan(const int* __restrict__ blockHist,
                                               int* __restrict__ blockOff,
                                               int* __restrict__ bucketStart,
                                               int* __restrict__ rowptr, int e, int n) {
    __shared__ int tot[NBINS];
    int bin = threadIdx.x;
    int s = 0;
    for (int b = 0; b < BPART; b++) {
        int v = blockHist[b * NBINS + bin];
        blockOff[b * NBINS + bin] = s;   // coalesced (bin contiguous across threads)
        s += v;
    }
    tot[bin] = s;
    __syncthreads();
    if (bin == 0) {
        int acc = 0;
        for (int i = 0; i < NBINS; i++) { int v = tot[i]; tot[i] = acc; acc += v; }
        rowptr[n] = e;
    }
    __syncthreads();
    bucketStart[bin] = tot[bin];
    if (bin == 0) bucketStart[NBINS] = e;
}

// ---------- Pass C: scatter edges into bucket-sorted order (packed) ----------
__global__ __launch_bounds__(1024) void k_scat(const int* __restrict__ row,
                                               const int* __restrict__ col,
                                               const int* __restrict__ blockOff,
                                               const int* __restrict__ bucketStart,
                                               int* __restrict__ ebuf, int e) {
    __shared__ int c2[NBINS];
    for (int i = threadIdx.x; i < NBINS; i += 1024) c2[i] = 0;
    __syncthreads();
    int chunk = cdiv(e, gridDim.x);
    int s = blockIdx.x * chunk, t = min(e, s + chunk);
    const int* boff = blockOff + blockIdx.x * NBINS;
    for (int i = s + threadIdx.x; i < t; i += 1024) {
        int c = col[i];
        int bin = c >> 7;
        int lr = atomicAdd(&c2[bin], 1);                 // LDS atomic — cheap
        int pos = bucketStart[bin] + boff[bin] + lr;     // globally unique
        ebuf[pos] = row[i] | ((c & 127) << 17);          // row<2^17, 7-bit local node
    }
}

// ---------- Pass D: per-bucket compact CSR (in place) + deg + fused z0 init ----------
__global__ __launch_bounds__(256) void k_csr(const int* __restrict__ bucketStart,
                                             int* __restrict__ ebuf,
                                             int* __restrict__ rowptr, int* __restrict__ deg,
                                             const float* __restrict__ pos,
                                             float4* __restrict__ z0, int n) {
    __shared__ int eb[LDSCAP];
    __shared__ int cnt[128];
    __shared__ int lptr[128];
    int g = blockIdx.x;
    int s0 = bucketStart[g], s1 = bucketStart[g + 1];
    int m = s1 - s0; if (m > LDSCAP) m = LDSCAP;
    for (int i = threadIdx.x; i < m; i += 256) eb[i] = ebuf[s0 + i];
    if (threadIdx.x < 128) cnt[threadIdx.x] = 0;
    __syncthreads();
    for (int i = threadIdx.x; i < m; i += 256) atomicAdd(&cnt[(eb[i] >> 17) & 127], 1);
    __syncthreads();
    if (threadIdx.x == 0) {
        int acc = 0;
        for (int i = 0; i < 128; i++) { lptr[i] = acc; acc += cnt[i]; }
    }
    __syncthreads();
    int node = g * 128 + threadIdx.x;
    if (threadIdx.x < 128 && node < n) {
        rowptr[node] = s0 + lptr[threadIdx.x];
        int d = cnt[threadIdx.x];
        deg[node] = d;
        float dis = rsqrtf((float)(d + 1));
        z0[node] = make_float4(dis * pos[3 * node], dis * pos[3 * node + 1],
                               dis * pos[3 * node + 2], 0.f);
    }
    if (threadIdx.x < 128) cnt[threadIdx.x] = 0;
    __syncthreads();
    for (int i = threadIdx.x; i < m; i += 256) {
        int v = eb[i];
        int t7 = (v >> 17) & 127;
        int slot = lptr[t7] + atomicAdd(&cnt[t7], 1);
        ebuf[s0 + slot] = v & 0x1FFFF;    // safe: whole range already staged in LDS
    }
}

// ---------- gather pass, 8 threads per node ----------
// non-final: z' = (z + sum_neigh) / deg_tot; final: * rsqrt(deg_tot) (x = D^{1/2} z_K)
template <bool FINAL>
__global__ __launch_bounds__(256) void k_gather8(
    const int* __restrict__ adj, const int* __restrict__ rowptr,
    const float4* __restrict__ zin, float4* __restrict__ zout,
    double* stats, int n) {
    int gid = blockIdx.x * 256 + threadIdx.x;
    int node = gid >> 3, sub = gid & 7;
    float x0 = 0.f, x1 = 0.f, x2 = 0.f;   // only sub==0 lanes hold a valid node value
    if (node < n) {
        int s = rowptr[node], t = rowptr[node + 1];
        float s0 = 0.f, s1 = 0.f, s2 = 0.f;
        for (int j = s + sub; j < t; j += 8) {   // lanes 0..7 hit adjacent words: coalesced
            float4 a = zin[adj[j]];
            s0 += a.x; s1 += a.y; s2 += a.z;
        }
#pragma unroll
        for (int m = 1; m < 8; m <<= 1) {        // fold 8 partials within the lane-octet
            s0 += __shfl_xor(s0, m, 64);
            s1 += __shfl_xor(s1, m, 64);
            s2 += __shfl_xor(s2, m, 64);
        }
        if (sub == 0) {
            float4 zi = zin[node];               // self loop
            float dg = (float)(t - s + 1);
            float sc = FINAL ? rsqrtf(dg) : (1.0f / dg);
            x0 = sc * (s0 + zi.x); x1 = sc * (s1 + zi.y); x2 = sc * (s2 + zi.z);
            zout[node] = make_float4(x0, x1, x2, 0.f);
        }
    }
    if (FINAL) {
        // non-writer lanes contribute zeros — sums over nodes stay exact
        double v[9];
        v[0] = x0; v[1] = x1; v[2] = x2;
        v[3] = (double)x0 * x0; v[4] = (double)x0 * x1; v[5] = (double)x0 * x2;
        v[6] = (double)x1 * x1; v[7] = (double)x1 * x2; v[8] = (double)x2 * x2;
#pragma unroll
        for (int jj = 0; jj < 9; jj++) {
            double t = v[jj];
            for (int m = 1; m < 64; m <<= 1) t += __shfl_xor(t, m, 64);
            if ((threadIdx.x & 63) == 0) atomicAdd(&stats[jj], t);
        }
    }
}

// ---------- graph boundaries via binary search (batch is sorted) ----------
__global__ void k_bounds(const int* __restrict__ batch, int* starts, int n) {
    int g = threadIdx.x;
    if (g <= GG) {
        int lo = 0, hi = n;
        while (lo < hi) {
            int mid = (lo + hi) >> 1;
            if (batch[mid] < g) lo = mid + 1; else hi = mid;
        }
        starts[g] = lo;
    }
}

// ---------- pooling: per (graph, channel) max/min of dot(x, W_c), fused BN0+ReLU ----------
__global__ __launch_bounds__(256) void k_pool(
    const float4* __restrict__ z, const int* __restrict__ starts,
    const float* __restrict__ lin_w,
    const float* __restrict__ bn0_g, const float* __restrict__ bn0_b,
    const double* __restrict__ stats, float* pooled, int n) {
    __shared__ float4 sh[TILE];
    int g = blockIdx.x;
    int c = blockIdx.y * 256 + threadIdx.x;

    float w0 = lin_w[c], w1 = lin_w[HID + c], w2 = lin_w[2 * HID + c];

    double invN = 1.0 / (double)n;
    double mu0 = stats[0] * invN, mu1 = stats[1] * invN, mu2 = stats[2] * invN;
    float c00 = (float)(stats[3] * invN - mu0 * mu0);
    float c01 = (float)(stats[4] * invN - mu0 * mu1);
    float c02 = (float)(stats[5] * invN - mu0 * mu2);
    float c11 = (float)(stats[6] * invN - mu1 * mu1);
    float c12 = (float)(stats[7] * invN - mu1 * mu2);
    float c22 = (float)(stats[8] * invN - mu2 * mu2);
    float meanc = (float)mu0 * w0 + (float)mu1 * w1 + (float)mu2 * w2;  // lin_b cancels in BN
    float var = c00 * w0 * w0 + c11 * w1 * w1 + c22 * w2 * w2
              + 2.f * (c01 * w0 * w1 + c02 * w0 * w2 + c12 * w1 * w2);
    var = fmaxf(var, 0.f);

    int s0 = starts[g], s1 = starts[g + 1];
    float mx = -INFINITY, mn = INFINITY;
    for (int base = s0; base < s1; base += TILE) {
        int cnt = min(TILE, s1 - base);
        __syncthreads();
        for (int j = threadIdx.x; j < cnt; j += 256) sh[j] = z[base + j];
        __syncthreads();
        for (int j = 0; j < cnt; j++) {
            float4 p = sh[j];
            float d = fmaf(p.x, w0, fmaf(p.y, w1, p.z * w2));
            mx = fmaxf(mx, d);
            mn = fminf(mn, d);
        }
    }
    float inv = rsqrtf(var + BNEPS);
    float s = bn0_g[c] * inv;
    float raw = (s >= 0.f) ? mx : mn;     // BN scale sign decides which extreme survives relu∘max
    float y = (raw - meanc) * s + bn0_b[c];
    pooled[g * HID + c] = fmaxf(y, 0.f);
}

// ---------- fused Linear + BN(over 64 rows = 1 wave) + ReLU; 1 wave per output column ----------
template <int KIN>
__global__ __launch_bounds__(64) void k_fcbn(
    const float* __restrict__ in, const float* __restrict__ W,
    const float* __restrict__ bias, const float* __restrict__ gamma,
    const float* __restrict__ beta, float* out, int Cout) {
    int c = blockIdx.x;
    int r = threadIdx.x;  // 64 rows == wave size
    const float* rowp = in + r * KIN;
    float acc = 0.f;
#pragma unroll 8
    for (int k = 0; k < KIN; k++) acc = fmaf(rowp[k], W[k * Cout + c], acc);
    float y = acc + bias[c];
    float sum = y, sq = y * y;
    for (int m = 1; m < 64; m <<= 1) {
        sum += __shfl_xor(sum, m, 64);
        sq  += __shfl_xor(sq, m, 64);
    }
    float mean = sum * (1.f / 64.f);
    float var  = fmaxf(sq * (1.f / 64.f) - mean * mean, 0.f);
    float o = (y - mean) * rsqrtf(var + BNEPS) * gamma[c] + beta[c];
    out[r * Cout + c] = fmaxf(o, 0.f);
}

// ---------- fc3 + log_softmax; 1 wave per row ----------
__global__ __launch_bounds__(64) void k_out(
    const float* __restrict__ in, const float* __restrict__ W,
    const float* __restrict__ bias, float* out) {
    int r = blockIdx.x;
    int c = threadIdx.x;
    bool act = c < NCLS;
    float z = -INFINITY;
    if (act) {
        const float* rowp = in + r * H2;
        float acc = 0.f;
#pragma unroll 8
        for (int k = 0; k < H2; k++) acc = fmaf(rowp[k], W[k * NCLS + c], acc);
        z = acc + bias[c];
    }
    float mx = z;
    for (int m = 1; m < 64; m <<= 1) mx = fmaxf(mx, __shfl_xor(mx, m, 64));
    float ex = act ? expf(z - mx) : 0.f;
    float se = ex;
    for (int m = 1; m < 64; m <<= 1) se += __shfl_xor(se, m, 64);
    if (act) out[r * NCLS + c] = z - mx - logf(se);
}

extern "C" void kernel_launch(void* const* d_in, const int* in_sizes, int n_in,
                              void* d_out, int out_size, void* d_ws, size_t ws_size,
                              hipStream_t stream) {
    const float* pos   = (const float*)d_in[0];
    const int*   ei    = (const int*)d_in[1];   // [2,E]: rows at [0,E), cols at [E,2E)
    const int*   batch = (const int*)d_in[2];
    const float* lin_w = (const float*)d_in[3];
    // d_in[4] lin_b cancels in BN0 centering
    const float* bn0_g = (const float*)d_in[5];
    const float* bn0_b = (const float*)d_in[6];
    const float* fc1_w = (const float*)d_in[7];
    const float* fc1_b = (const float*)d_in[8];
    const float* bn1_g = (const float*)d_in[9];
    const float* bn1_b = (const float*)d_in[10];
    const float* fc2_w = (const float*)d_in[11];
    const float* fc2_b = (const float*)d_in[12];
    const float* bn2_g = (const float*)d_in[13];
    const float* bn2_b = (const float*)d_in[14];
    const float* fc3_w = (const float*)d_in[15];
    const float* fc3_b = (const float*)d_in[16];

    int n = in_sizes[0] / 3;
    int e = in_sizes[1] / 2;
    int nbuck = cdiv(n, 128);

    auto align256 = [](size_t x) { return (x + 255) & ~(size_t)255; };
    char* w = (char*)d_ws;
    int*    blockHist = (int*)w;    w += align256((size_t)BPART * NBINS * 4);
    int*    blockOff  = (int*)w;    w += align256((size_t)BPART * NBINS * 4);
    int*    bucketSt  = (int*)w;    w += align256((NBINS + 1) * 4);
    int*    rowptr    = (int*)w;    w += align256((size_t)(n + 1) * 4);
    int*    deg       = (int*)w;    w += align256((size_t)n * 4);
    int*    ebuf      = (int*)w;    w += align256((size_t)e * 4);
    float4* za        = (float4*)w; w += align256((size_t)n * 16);
    float4* zb        = (float4*)w; w += align256((size_t)n * 16);
    double* stats     = (double*)w; w += align256(9 * sizeof(double));
    int*    starts    = (int*)w;    w += align256((GG + 1) * 4);
    float*  pooled    = (float*)w;  w += align256((size_t)GG * HID * 4);
    float*  h1        = (float*)w;  w += align256((size_t)GG * H1 * 4);
    float*  h2        = (float*)w;  w += align256((size_t)GG * H2 * 4);

    (void)hipMemsetAsync(stats, 0, 9 * sizeof(double), stream);

    const int* erow = ei;
    const int* ecol = ei + e;

    k_hista<<<BPART, 1024, 0, stream>>>(ecol, blockHist, e);
    k_scan <<<1, NBINS, 0, stream>>>(blockHist, blockOff, bucketSt, rowptr, e, n);
    k_scat <<<BPART, 1024, 0, stream>>>(erow, ecol, blockOff, bucketSt, ebuf, e);
    k_csr  <<<nbuck, 256, 0, stream>>>(bucketSt, ebuf, rowptr, deg, pos, za, n);

    int gn8 = cdiv(n * 8, 256);
    // K=5 passes, double-buffered: za->zb->za->zb->za->zb (final in zb)
    k_gather8<false><<<gn8, 256, 0, stream>>>(ebuf, rowptr, za, zb, stats, n);
    k_gather8<false><<<gn8, 256, 0, stream>>>(ebuf, rowptr, zb, za, stats, n);
    k_gather8<false><<<gn8, 256, 0, stream>>>(ebuf, rowptr, za, zb, stats, n);
    k_gather8<false><<<gn8, 256, 0, stream>>>(ebuf, rowptr, zb, za, stats, n);
    k_gather8<true ><<<gn8, 256, 0, stream>>>(ebuf, rowptr, za, zb, stats, n);

    k_bounds<<<1, 128, 0, stream>>>(batch, starts, n);
    k_pool<<<dim3(GG, HID / 256), 256, 0, stream>>>(zb, starts, lin_w, bn0_g, bn0_b, stats, pooled, n);
    k_fcbn<HID><<<H1, 64, 0, stream>>>(pooled, fc1_w, fc1_b, bn1_g, bn1_b, h1, H1);
    k_fcbn<H1><<<H2, 64, 0, stream>>>(h1, fc2_w, fc2_b, bn2_g, bn2_b, h2, H2);
    k_out<<<GG, 64, 0, stream>>>(h2, fc3_w, fc3_b, (float*)d_out);
}

// Round 6
// 1028.545 us; speedup vs baseline: 1.6017x; 1.6017x over previous
//
#include <hip/hip_runtime.h>
#include <math.h>

#define HID    1024
#define GG     64
#define KPROP  5
#define H1     512
#define H2     256
#define NCLS   40
#define BNEPS  1e-5f
#define TILE   2048
#define BPART  256     // partition blocks
#define NBINS  1024    // buckets of 128 nodes (supports n <= 131072)
#define LDSCAP 8192    // max edges per bucket staged in LDS (mean ~4096, sd ~64)

__host__ __device__ static inline int cdiv(int a, int b) { return (a + b - 1) / b; }

// ---------- Pass A: per-block histogram of col>>7 ----------
__global__ __launch_bounds__(1024) void k_hista(const int* __restrict__ col,
                                                int* __restrict__ blockHist, int e) {
    __shared__ int h[NBINS];
    for (int i = threadIdx.x; i < NBINS; i += 1024) h[i] = 0;
    __syncthreads();
    int chunk = cdiv(e, gridDim.x);
    int s = blockIdx.x * chunk, t = min(e, s + chunk);
    for (int i = s + threadIdx.x; i < t; i += 1024) atomicAdd(&h[col[i] >> 7], 1);
    __syncthreads();
    for (int i = threadIdx.x; i < NBINS; i += 1024)
        blockHist[blockIdx.x * NBINS + i] = h[i];
}

// ---------- Pass B: per-(block,bucket) exclusive offsets + bucket starts ----------
__global__ __launch_bounds__(1024) void k_scan(const int* __restrict__ blockHist,
                                               int* __restrict__ blockOff,
                                               int* __restrict__ bucketStart,
                                               int* __restrict__ rowptr, int e, int n) {
    __shared__ int tot[NBINS];
    int bin = threadIdx.x;
    int s = 0;
    for (int b = 0; b < BPART; b++) {
        int v = blockHist[b * NBINS + bin];
        blockOff[b * NBINS + bin] = s;   // coalesced (bin contiguous across threads)
        s += v;
    }
    tot[bin] = s;
    __syncthreads();
    if (bin == 0) {
        int acc = 0;
        for (int i = 0; i < NBINS; i++) { int v = tot[i]; tot[i] = acc; acc += v; }
        rowptr[n] = e;
    }
    __syncthreads();
    bucketStart[bin] = tot[bin];
    if (bin == 0) bucketStart[NBINS] = e;
}

// ---------- Pass C: scatter edges into bucket-sorted order (packed) ----------
__global__ __launch_bounds__(1024) void k_scat(const int* __restrict__ row,
                                               const int* __restrict__ col,
                                               const int* __restrict__ blockOff,
                                               const int* __restrict__ bucketStart,
                                               int* __restrict__ ebuf, int e) {
    __shared__ int c2[NBINS];
    for (int i = threadIdx.x; i < NBINS; i += 1024) c2[i] = 0;
    __syncthreads();
    int chunk = cdiv(e, gridDim.x);
    int s = blockIdx.x * chunk, t = min(e, s + chunk);
    const int* boff = blockOff + blockIdx.x * NBINS;
    for (int i = s + threadIdx.x; i < t; i += 1024) {
        int c = col[i];
        int bin = c >> 7;
        int lr = atomicAdd(&c2[bin], 1);                 // LDS atomic — cheap
        int pos = bucketStart[bin] + boff[bin] + lr;     // globally unique
        ebuf[pos] = row[i] | ((c & 127) << 17);          // row<2^17, 7-bit local node
    }
}

// ---------- Pass D: per-bucket compact CSR (in place) + deg + fused z0 init ----------
__global__ __launch_bounds__(256) void k_csr(const int* __restrict__ bucketStart,
                                             int* __restrict__ ebuf,
                                             int* __restrict__ rowptr, int* __restrict__ deg,
                                             const float* __restrict__ pos,
                                             float4* __restrict__ z0, int n) {
    __shared__ int eb[LDSCAP];
    __shared__ int cnt[128];
    __shared__ int lptr[128];
    int g = blockIdx.x;
    int s0 = bucketStart[g], s1 = bucketStart[g + 1];
    int m = s1 - s0; if (m > LDSCAP) m = LDSCAP;
    for (int i = threadIdx.x; i < m; i += 256) eb[i] = ebuf[s0 + i];
    if (threadIdx.x < 128) cnt[threadIdx.x] = 0;
    __syncthreads();
    for (int i = threadIdx.x; i < m; i += 256) atomicAdd(&cnt[(eb[i] >> 17) & 127], 1);
    __syncthreads();
    if (threadIdx.x == 0) {
        int acc = 0;
        for (int i = 0; i < 128; i++) { lptr[i] = acc; acc += cnt[i]; }
    }
    __syncthreads();
    int node = g * 128 + threadIdx.x;
    if (threadIdx.x < 128 && node < n) {
        rowptr[node] = s0 + lptr[threadIdx.x];
        int d = cnt[threadIdx.x];
        deg[node] = d;
        float dis = rsqrtf((float)(d + 1));
        z0[node] = make_float4(dis * pos[3 * node], dis * pos[3 * node + 1],
                               dis * pos[3 * node + 2], 0.f);
    }
    if (threadIdx.x < 128) cnt[threadIdx.x] = 0;
    __syncthreads();
    for (int i = threadIdx.x; i < m; i += 256) {
        int v = eb[i];
        int t7 = (v >> 17) & 127;
        int slot = lptr[t7] + atomicAdd(&cnt[t7], 1);
        ebuf[s0 + slot] = v & 0x1FFFF;    // safe: whole range already staged in LDS
    }
}

// ---------- gather pass, 4 lanes per node, ILP-4 per lane ----------
// Lane `sub` owns interleaved 4-neighbor chunks: [s+sub*4+16k, +4). Per iteration:
// 4 independent adj loads then 4 independent zin loads in flight (compiler batches
// waitcnt), so the serial chain per node is ~deg/16 iterations, not deg.
template <bool FINAL>
__global__ __launch_bounds__(256) void k_gather4(
    const int* __restrict__ adj, const int* __restrict__ rowptr,
    const float4* __restrict__ zin, float4* __restrict__ zout,
    double* stats, int n) {
    int gid = blockIdx.x * 256 + threadIdx.x;
    int node = gid >> 2, sub = gid & 3;
    float x0 = 0.f, x1 = 0.f, x2 = 0.f;   // only sub==0 lanes hold a valid value
    if (node < n) {
        int s = rowptr[node], t = rowptr[node + 1];
        float s0 = 0.f, s1 = 0.f, s2 = 0.f;
        for (int j0 = s + sub * 4; j0 < t; j0 += 16) {
            if (j0 + 4 <= t) {
                int r0 = adj[j0], r1 = adj[j0 + 1], r2 = adj[j0 + 2], r3 = adj[j0 + 3];
                float4 a = zin[r0], b = zin[r1], c = zin[r2], d = zin[r3];
                s0 += a.x + b.x + c.x + d.x;
                s1 += a.y + b.y + c.y + d.y;
                s2 += a.z + b.z + c.z + d.z;
            } else {
                for (int j = j0; j < t; j++) {
                    float4 a = zin[adj[j]];
                    s0 += a.x; s1 += a.y; s2 += a.z;
                }
            }
        }
#pragma unroll
        for (int m = 1; m < 4; m <<= 1) {   // fold 4 partials within the lane-quad
            s0 += __shfl_xor(s0, m, 64);
            s1 += __shfl_xor(s1, m, 64);
            s2 += __shfl_xor(s2, m, 64);
        }
        if (sub == 0) {
            float4 zi = zin[node];           // self loop
            float dg = (float)(t - s + 1);
            float sc = FINAL ? rsqrtf(dg) : (1.0f / dg);
            x0 = sc * (s0 + zi.x); x1 = sc * (s1 + zi.y); x2 = sc * (s2 + zi.z);
            zout[node] = make_float4(x0, x1, x2, 0.f);
        }
    }
    if (FINAL) {
        // non-writer lanes contribute zeros — sums over nodes stay exact
        double v[9];
        v[0] = x0; v[1] = x1; v[2] = x2;
        v[3] = (double)x0 * x0; v[4] = (double)x0 * x1; v[5] = (double)x0 * x2;
        v[6] = (double)x1 * x1; v[7] = (double)x1 * x2; v[8] = (double)x2 * x2;
#pragma unroll
        for (int jj = 0; jj < 9; jj++) {
            double t = v[jj];
            for (int m = 1; m < 64; m <<= 1) t += __shfl_xor(t, m, 64);
            if ((threadIdx.x & 63) == 0) atomicAdd(&stats[jj], t);
        }
    }
}

// ---------- graph boundaries via binary search (batch is sorted) ----------
__global__ void k_bounds(const int* __restrict__ batch, int* starts, int n) {
    int g = threadIdx.x;
    if (g <= GG) {
        int lo = 0, hi = n;
        while (lo < hi) {
            int mid = (lo + hi) >> 1;
            if (batch[mid] < g) lo = mid + 1; else hi = mid;
        }
        starts[g] = lo;
    }
}

// ---------- pooling: per (graph, channel) max/min of dot(x, W_c), fused BN0+ReLU ----------
__global__ __launch_bounds__(256) void k_pool(
    const float4* __restrict__ z, const int* __restrict__ starts,
    const float* __restrict__ lin_w,
    const float* __restrict__ bn0_g, const float* __restrict__ bn0_b,
    const double* __restrict__ stats, float* pooled, int n) {
    __shared__ float4 sh[TILE];
    int g = blockIdx.x;
    int c = blockIdx.y * 256 + threadIdx.x;

    float w0 = lin_w[c], w1 = lin_w[HID + c], w2 = lin_w[2 * HID + c];

    double invN = 1.0 / (double)n;
    double mu0 = stats[0] * invN, mu1 = stats[1] * invN, mu2 = stats[2] * invN;
    float c00 = (float)(stats[3] * invN - mu0 * mu0);
    float c01 = (float)(stats[4] * invN - mu0 * mu1);
    float c02 = (float)(stats[5] * invN - mu0 * mu2);
    float c11 = (float)(stats[6] * invN - mu1 * mu1);
    float c12 = (float)(stats[7] * invN - mu1 * mu2);
    float c22 = (float)(stats[8] * invN - mu2 * mu2);
    float meanc = (float)mu0 * w0 + (float)mu1 * w1 + (float)mu2 * w2;  // lin_b cancels in BN
    float var = c00 * w0 * w0 + c11 * w1 * w1 + c22 * w2 * w2
              + 2.f * (c01 * w0 * w1 + c02 * w0 * w2 + c12 * w1 * w2);
    var = fmaxf(var, 0.f);

    int s0 = starts[g], s1 = starts[g + 1];
    float mx = -INFINITY, mn = INFINITY;
    for (int base = s0; base < s1; base += TILE) {
        int cnt = min(TILE, s1 - base);
        __syncthreads();
        for (int j = threadIdx.x; j < cnt; j += 256) sh[j] = z[base + j];
        __syncthreads();
        for (int j = 0; j < cnt; j++) {
            float4 p = sh[j];
            float d = fmaf(p.x, w0, fmaf(p.y, w1, p.z * w2));
            mx = fmaxf(mx, d);
            mn = fminf(mn, d);
        }
    }
    float inv = rsqrtf(var + BNEPS);
    float s = bn0_g[c] * inv;
    float raw = (s >= 0.f) ? mx : mn;     // BN scale sign decides which extreme survives relu∘max
    float y = (raw - meanc) * s + bn0_b[c];
    pooled[g * HID + c] = fmaxf(y, 0.f);
}

// ---------- fused Linear + BN(over 64 rows = 1 wave) + ReLU; 1 wave per output column ----------
template <int KIN>
__global__ __launch_bounds__(64) void k_fcbn(
    const float* __restrict__ in, const float* __restrict__ W,
    const float* __restrict__ bias, const float* __restrict__ gamma,
    const float* __restrict__ beta, float* out, int Cout) {
    int c = blockIdx.x;
    int r = threadIdx.x;  // 64 rows == wave size
    const float* rowp = in + r * KIN;
    float acc = 0.f;
#pragma unroll 8
    for (int k = 0; k < KIN; k++) acc = fmaf(rowp[k], W[k * Cout + c], acc);
    float y = acc + bias[c];
    float sum = y, sq = y * y;
    for (int m = 1; m < 64; m <<= 1) {
        sum += __shfl_xor(sum, m, 64);
        sq  += __shfl_xor(sq, m, 64);
    }
    float mean = sum * (1.f / 64.f);
    float var  = fmaxf(sq * (1.f / 64.f) - mean * mean, 0.f);
    float o = (y - mean) * rsqrtf(var + BNEPS) * gamma[c] + beta[c];
    out[r * Cout + c] = fmaxf(o, 0.f);
}

// ---------- fc3 + log_softmax; 1 wave per row ----------
__global__ __launch_bounds__(64) void k_out(
    const float* __restrict__ in, const float* __restrict__ W,
    const float* __restrict__ bias, float* out) {
    int r = blockIdx.x;
    int c = threadIdx.x;
    bool act = c < NCLS;
    float z = -INFINITY;
    if (act) {
        const float* rowp = in + r * H2;
        float acc = 0.f;
#pragma unroll 8
        for (int k = 0; k < H2; k++) acc = fmaf(rowp[k], W[k * NCLS + c], acc);
        z = acc + bias[c];
    }
    float mx = z;
    for (int m = 1; m < 64; m <<= 1) mx = fmaxf(mx, __shfl_xor(mx, m, 64));
    float ex = act ? expf(z - mx) : 0.f;
    float se = ex;
    for (int m = 1; m < 64; m <<= 1) se += __shfl_xor(se, m, 64);
    if (act) out[r * NCLS + c] = z - mx - logf(se);
}

extern "C" void kernel_launch(void* const* d_in, const int* in_sizes, int n_in,
                              void* d_out, int out_size, void* d_ws, size_t ws_size,
                              hipStream_t stream) {
    const float* pos   = (const float*)d_in[0];
    const int*   ei    = (const int*)d_in[1];   // [2,E]: rows at [0,E), cols at [E,2E)
    const int*   batch = (const int*)d_in[2];
    const float* lin_w = (const float*)d_in[3];
    // d_in[4] lin_b cancels in BN0 centering
    const float* bn0_g = (const float*)d_in[5];
    const float* bn0_b = (const float*)d_in[6];
    const float* fc1_w = (const float*)d_in[7];
    const float* fc1_b = (const float*)d_in[8];
    const float* bn1_g = (const float*)d_in[9];
    const float* bn1_b = (const float*)d_in[10];
    const float* fc2_w = (const float*)d_in[11];
    const float* fc2_b = (const float*)d_in[12];
    const float* bn2_g = (const float*)d_in[13];
    const float* bn2_b = (const float*)d_in[14];
    const float* fc3_w = (const float*)d_in[15];
    const float* fc3_b = (const float*)d_in[16];

    int n = in_sizes[0] / 3;
    int e = in_sizes[1] / 2;
    int nbuck = cdiv(n, 128);

    auto align256 = [](size_t x) { return (x + 255) & ~(size_t)255; };
    char* w = (char*)d_ws;
    int*    blockHist = (int*)w;    w += align256((size_t)BPART * NBINS * 4);
    int*    blockOff  = (int*)w;    w += align256((size_t)BPART * NBINS * 4);
    int*    bucketSt  = (int*)w;    w += align256((NBINS + 1) * 4);
    int*    rowptr    = (int*)w;    w += align256((size_t)(n + 1) * 4);
    int*    deg       = (int*)w;    w += align256((size_t)n * 4);
    int*    ebuf      = (int*)w;    w += align256((size_t)e * 4);
    float4* za        = (float4*)w; w += align256((size_t)n * 16);
    float4* zb        = (float4*)w; w += align256((size_t)n * 16);
    double* stats     = (double*)w; w += align256(9 * sizeof(double));
    int*    starts    = (int*)w;    w += align256((GG + 1) * 4);
    float*  pooled    = (float*)w;  w += align256((size_t)GG * HID * 4);
    float*  h1        = (float*)w;  w += align256((size_t)GG * H1 * 4);
    float*  h2        = (float*)w;  w += align256((size_t)GG * H2 * 4);

    (void)hipMemsetAsync(stats, 0, 9 * sizeof(double), stream);

    const int* erow = ei;
    const int* ecol = ei + e;

    k_hista<<<BPART, 1024, 0, stream>>>(ecol, blockHist, e);
    k_scan <<<1, NBINS, 0, stream>>>(blockHist, blockOff, bucketSt, rowptr, e, n);
    k_scat <<<BPART, 1024, 0, stream>>>(erow, ecol, blockOff, bucketSt, ebuf, e);
    k_csr  <<<nbuck, 256, 0, stream>>>(bucketSt, ebuf, rowptr, deg, pos, za, n);

    int gn4 = cdiv(n * 4, 256);
    // K=5 passes, double-buffered: za->zb->za->zb->za->zb (final in zb)
    k_gather4<false><<<gn4, 256, 0, stream>>>(ebuf, rowptr, za, zb, stats, n);
    k_gather4<false><<<gn4, 256, 0, stream>>>(ebuf, rowptr, zb, za, stats, n);
    k_gather4<false><<<gn4, 256, 0, stream>>>(ebuf, rowptr, za, zb, stats, n);
    k_gather4<false><<<gn4, 256, 0, stream>>>(ebuf, rowptr, zb, za, stats, n);
    k_gather4<true ><<<gn4, 256, 0, stream>>>(ebuf, rowptr, za, zb, stats, n);

    k_bounds<<<1, 128, 0, stream>>>(batch, starts, n);
    k_pool<<<dim3(GG, HID / 256), 256, 0, stream>>>(zb, starts, lin_w, bn0_g, bn0_b, stats, pooled, n);
    k_fcbn<HID><<<H1, 64, 0, stream>>>(pooled, fc1_w, fc1_b, bn1_g, bn1_b, h1, H1);
    k_fcbn<H1><<<H2, 64, 0, stream>>>(h1, fc2_w, fc2_b, bn2_g, bn2_b, h2, H2);
    k_out<<<GG, 64, 0, stream>>>(h2, fc3_w, fc3_b, (float*)d_out);
}

// Round 7
// 564.076 us; speedup vs baseline: 2.9206x; 1.8234x over previous
//
#include <hip/hip_runtime.h>
#include <math.h>

#define HID    1024
#define GG     64
#define KPROP  5
#define H1     512
#define H2     256
#define NCLS   40
#define BNEPS  1e-5f
#define TILE   2048
#define BPART  256     // partition blocks
#define NBINS  1024    // buckets of 128 nodes (supports n <= 131072)
#define LDSCAP 8192    // max edges per bucket staged in LDS (mean ~4096, sd ~64)

__host__ __device__ static inline int cdiv(int a, int b) { return (a + b - 1) / b; }

// ---------- Pass A: per-block histogram of col>>7 ----------
__global__ __launch_bounds__(1024) void k_hista(const int* __restrict__ col,
                                                int* __restrict__ blockHist, int e) {
    __shared__ int h[NBINS];
    for (int i = threadIdx.x; i < NBINS; i += 1024) h[i] = 0;
    __syncthreads();
    int chunk = cdiv(e, gridDim.x);
    int s = blockIdx.x * chunk, t = min(e, s + chunk);
    for (int i = s + threadIdx.x; i < t; i += 1024) atomicAdd(&h[col[i] >> 7], 1);
    __syncthreads();
    for (int i = threadIdx.x; i < NBINS; i += 1024)
        blockHist[blockIdx.x * NBINS + i] = h[i];
}

// ---------- Pass B: per-(block,bucket) exclusive offsets + bucket starts ----------
__global__ __launch_bounds__(1024) void k_scan(const int* __restrict__ blockHist,
                                               int* __restrict__ blockOff,
                                               int* __restrict__ bucketStart,
                                               int* __restrict__ rowptr, int e, int n) {
    __shared__ int tot[NBINS];
    int bin = threadIdx.x;
    int s = 0;
    for (int b = 0; b < BPART; b++) {
        int v = blockHist[b * NBINS + bin];
        blockOff[b * NBINS + bin] = s;   // coalesced (bin contiguous across threads)
        s += v;
    }
    tot[bin] = s;
    __syncthreads();
    if (bin == 0) {
        int acc = 0;
        for (int i = 0; i < NBINS; i++) { int v = tot[i]; tot[i] = acc; acc += v; }
        rowptr[n] = e;
    }
    __syncthreads();
    bucketStart[bin] = tot[bin];
    if (bin == 0) bucketStart[NBINS] = e;
}

// ---------- Pass C: scatter edges into bucket-sorted order (packed) ----------
__global__ __launch_bounds__(1024) void k_scat(const int* __restrict__ row,
                                               const int* __restrict__ col,
                                               const int* __restrict__ blockOff,
                                               const int* __restrict__ bucketStart,
                                               int* __restrict__ ebuf, int e) {
    __shared__ int c2[NBINS];
    for (int i = threadIdx.x; i < NBINS; i += 1024) c2[i] = 0;
    __syncthreads();
    int chunk = cdiv(e, gridDim.x);
    int s = blockIdx.x * chunk, t = min(e, s + chunk);
    const int* boff = blockOff + blockIdx.x * NBINS;
    for (int i = s + threadIdx.x; i < t; i += 1024) {
        int c = col[i];
        int bin = c >> 7;
        int lr = atomicAdd(&c2[bin], 1);                 // LDS atomic — cheap
        int pos = bucketStart[bin] + boff[bin] + lr;     // globally unique
        ebuf[pos] = row[i] | ((c & 127) << 17);          // row<2^17, 7-bit local node
    }
}

// ---------- Pass D: per-bucket compact CSR (in place) + deg + fused z0 init ----------
__global__ __launch_bounds__(256) void k_csr(const int* __restrict__ bucketStart,
                                             int* __restrict__ ebuf,
                                             int* __restrict__ rowptr, int* __restrict__ deg,
                                             const float* __restrict__ pos,
                                             float4* __restrict__ z0, int n) {
    __shared__ int eb[LDSCAP];
    __shared__ int cnt[128];
    __shared__ int lptr[128];
    int g = blockIdx.x;
    int s0 = bucketStart[g], s1 = bucketStart[g + 1];
    int m = s1 - s0; if (m > LDSCAP) m = LDSCAP;
    for (int i = threadIdx.x; i < m; i += 256) eb[i] = ebuf[s0 + i];
    if (threadIdx.x < 128) cnt[threadIdx.x] = 0;
    __syncthreads();
    for (int i = threadIdx.x; i < m; i += 256) atomicAdd(&cnt[(eb[i] >> 17) & 127], 1);
    __syncthreads();
    if (threadIdx.x == 0) {
        int acc = 0;
        for (int i = 0; i < 128; i++) { lptr[i] = acc; acc += cnt[i]; }
    }
    __syncthreads();
    int node = g * 128 + threadIdx.x;
    if (threadIdx.x < 128 && node < n) {
        rowptr[node] = s0 + lptr[threadIdx.x];
        int d = cnt[threadIdx.x];
        deg[node] = d;
        float dis = rsqrtf((float)(d + 1));
        z0[node] = make_float4(dis * pos[3 * node], dis * pos[3 * node + 1],
                               dis * pos[3 * node + 2], 0.f);
    }
    if (threadIdx.x < 128) cnt[threadIdx.x] = 0;
    __syncthreads();
    for (int i = threadIdx.x; i < m; i += 256) {
        int v = eb[i];
        int t7 = (v >> 17) & 127;
        int slot = lptr[t7] + atomicAdd(&cnt[t7], 1);
        ebuf[s0 + slot] = v & 0x1FFFF;    // safe: whole range already staged in LDS
    }
}

// ---------- gather pass over compact CSR, thread-per-node, ILP-8 ----------
// Two independent int4 adj loads then 8 independent z-gathers per drain:
// serial chain per node ~ deg/8 × 2 latencies (R4's ILP-4 was deg/4 × 2).
template <bool FINAL>
__global__ __launch_bounds__(256) void k_gather(
    const int* __restrict__ adj, const int* __restrict__ rowptr,
    const float4* __restrict__ zin, float4* __restrict__ zout,
    double* stats, int n) {
    int i = blockIdx.x * blockDim.x + threadIdx.x;
    float x0 = 0.f, x1 = 0.f, x2 = 0.f;
    if (i < n) {
        int s = rowptr[i], t = rowptr[i + 1];
        float4 zi = zin[i];
        float s0 = zi.x, s1 = zi.y, s2 = zi.z;   // self loop
        float t0 = 0.f, t1 = 0.f, t2 = 0.f;
        int j = s;
        for (; j + 8 <= t; j += 8) {             // ILP-8: 8 z-gathers in flight
            int4 qa = *(const int4*)(adj + j);
            int4 qb = *(const int4*)(adj + j + 4);
            float4 a = zin[qa.x], b = zin[qa.y], c = zin[qa.z], d = zin[qa.w];
            float4 p = zin[qb.x], q = zin[qb.y], r = zin[qb.z], u = zin[qb.w];
            s0 += a.x + b.x + c.x + d.x;
            s1 += a.y + b.y + c.y + d.y;
            s2 += a.z + b.z + c.z + d.z;
            t0 += p.x + q.x + r.x + u.x;
            t1 += p.y + q.y + r.y + u.y;
            t2 += p.z + q.z + r.z + u.z;
        }
        if (j + 4 <= t) {                        // ILP-4 tail
            int4 qa = *(const int4*)(adj + j);
            float4 a = zin[qa.x], b = zin[qa.y], c = zin[qa.z], d = zin[qa.w];
            s0 += a.x + b.x + c.x + d.x;
            s1 += a.y + b.y + c.y + d.y;
            s2 += a.z + b.z + c.z + d.z;
            j += 4;
        }
        for (; j < t; j++) {
            float4 a = zin[adj[j]];
            s0 += a.x; s1 += a.y; s2 += a.z;
        }
        s0 += t0; s1 += t1; s2 += t2;
        float dg = (float)(t - s + 1);
        float sc = FINAL ? rsqrtf(dg) : (1.0f / dg);
        x0 = sc * s0; x1 = sc * s1; x2 = sc * s2;
        zout[i] = make_float4(x0, x1, x2, 0.f);
    }
    if (FINAL) {
        double v[9];
        v[0] = x0; v[1] = x1; v[2] = x2;
        v[3] = (double)x0 * x0; v[4] = (double)x0 * x1; v[5] = (double)x0 * x2;
        v[6] = (double)x1 * x1; v[7] = (double)x1 * x2; v[8] = (double)x2 * x2;
#pragma unroll
        for (int jj = 0; jj < 9; jj++) {
            double t = v[jj];
            for (int m = 1; m < 64; m <<= 1) t += __shfl_xor(t, m, 64);
            if ((threadIdx.x & 63) == 0) atomicAdd(&stats[jj], t);
        }
    }
}

// ---------- graph boundaries via binary search (batch is sorted) ----------
__global__ void k_bounds(const int* __restrict__ batch, int* starts, int n) {
    int g = threadIdx.x;
    if (g <= GG) {
        int lo = 0, hi = n;
        while (lo < hi) {
            int mid = (lo + hi) >> 1;
            if (batch[mid] < g) lo = mid + 1; else hi = mid;
        }
        starts[g] = lo;
    }
}

// ---------- pooling: per (graph, channel) max/min of dot(x, W_c), fused BN0+ReLU ----------
__global__ __launch_bounds__(256) void k_pool(
    const float4* __restrict__ z, const int* __restrict__ starts,
    const float* __restrict__ lin_w,
    const float* __restrict__ bn0_g, const float* __restrict__ bn0_b,
    const double* __restrict__ stats, float* pooled, int n) {
    __shared__ float4 sh[TILE];
    int g = blockIdx.x;
    int c = blockIdx.y * 256 + threadIdx.x;

    float w0 = lin_w[c], w1 = lin_w[HID + c], w2 = lin_w[2 * HID + c];

    double invN = 1.0 / (double)n;
    double mu0 = stats[0] * invN, mu1 = stats[1] * invN, mu2 = stats[2] * invN;
    float c00 = (float)(stats[3] * invN - mu0 * mu0);
    float c01 = (float)(stats[4] * invN - mu0 * mu1);
    float c02 = (float)(stats[5] * invN - mu0 * mu2);
    float c11 = (float)(stats[6] * invN - mu1 * mu1);
    float c12 = (float)(stats[7] * invN - mu1 * mu2);
    float c22 = (float)(stats[8] * invN - mu2 * mu2);
    float meanc = (float)mu0 * w0 + (float)mu1 * w1 + (float)mu2 * w2;  // lin_b cancels in BN
    float var = c00 * w0 * w0 + c11 * w1 * w1 + c22 * w2 * w2
              + 2.f * (c01 * w0 * w1 + c02 * w0 * w2 + c12 * w1 * w2);
    var = fmaxf(var, 0.f);

    int s0 = starts[g], s1 = starts[g + 1];
    float mx = -INFINITY, mn = INFINITY;
    for (int base = s0; base < s1; base += TILE) {
        int cnt = min(TILE, s1 - base);
        __syncthreads();
        for (int j = threadIdx.x; j < cnt; j += 256) sh[j] = z[base + j];
        __syncthreads();
        for (int j = 0; j < cnt; j++) {
            float4 p = sh[j];
            float d = fmaf(p.x, w0, fmaf(p.y, w1, p.z * w2));
            mx = fmaxf(mx, d);
            mn = fminf(mn, d);
        }
    }
    float inv = rsqrtf(var + BNEPS);
    float s = bn0_g[c] * inv;
    float raw = (s >= 0.f) ? mx : mn;     // BN scale sign decides which extreme survives relu∘max
    float y = (raw - meanc) * s + bn0_b[c];
    pooled[g * HID + c] = fmaxf(y, 0.f);
}

// ---------- fused Linear + BN(over 64 rows = 1 wave) + ReLU; 1 wave per output column ----------
template <int KIN>
__global__ __launch_bounds__(64) void k_fcbn(
    const float* __restrict__ in, const float* __restrict__ W,
    const float* __restrict__ bias, const float* __restrict__ gamma,
    const float* __restrict__ beta, float* out, int Cout) {
    int c = blockIdx.x;
    int r = threadIdx.x;  // 64 rows == wave size
    const float* rowp = in + r * KIN;
    float acc = 0.f;
#pragma unroll 8
    for (int k = 0; k < KIN; k++) acc = fmaf(rowp[k], W[k * Cout + c], acc);
    float y = acc + bias[c];
    float sum = y, sq = y * y;
    for (int m = 1; m < 64; m <<= 1) {
        sum += __shfl_xor(sum, m, 64);
        sq  += __shfl_xor(sq, m, 64);
    }
    float mean = sum * (1.f / 64.f);
    float var  = fmaxf(sq * (1.f / 64.f) - mean * mean, 0.f);
    float o = (y - mean) * rsqrtf(var + BNEPS) * gamma[c] + beta[c];
    out[r * Cout + c] = fmaxf(o, 0.f);
}

// ---------- fc3 + log_softmax; 1 wave per row ----------
__global__ __launch_bounds__(64) void k_out(
    const float* __restrict__ in, const float* __restrict__ W,
    const float* __restrict__ bias, float* out) {
    int r = blockIdx.x;
    int c = threadIdx.x;
    bool act = c < NCLS;
    float z = -INFINITY;
    if (act) {
        const float* rowp = in + r * H2;
        float acc = 0.f;
#pragma unroll 8
        for (int k = 0; k < H2; k++) acc = fmaf(rowp[k], W[k * NCLS + c], acc);
        z = acc + bias[c];
    }
    float mx = z;
    for (int m = 1; m < 64; m <<= 1) mx = fmaxf(mx, __shfl_xor(mx, m, 64));
    float ex = act ? expf(z - mx) : 0.f;
    float se = ex;
    for (int m = 1; m < 64; m <<= 1) se += __shfl_xor(se, m, 64);
    if (act) out[r * NCLS + c] = z - mx - logf(se);
}

extern "C" void kernel_launch(void* const* d_in, const int* in_sizes, int n_in,
                              void* d_out, int out_size, void* d_ws, size_t ws_size,
                              hipStream_t stream) {
    const float* pos   = (const float*)d_in[0];
    const int*   ei    = (const int*)d_in[1];   // [2,E]: rows at [0,E), cols at [E,2E)
    const int*   batch = (const int*)d_in[2];
    const float* lin_w = (const float*)d_in[3];
    // d_in[4] lin_b cancels in BN0 centering
    const float* bn0_g = (const float*)d_in[5];
    const float* bn0_b = (const float*)d_in[6];
    const float* fc1_w = (const float*)d_in[7];
    const float* fc1_b = (const float*)d_in[8];
    const float* bn1_g = (const float*)d_in[9];
    const float* bn1_b = (const float*)d_in[10];
    const float* fc2_w = (const float*)d_in[11];
    const float* fc2_b = (const float*)d_in[12];
    const float* bn2_g = (const float*)d_in[13];
    const float* bn2_b = (const float*)d_in[14];
    const float* fc3_w = (const float*)d_in[15];
    const float* fc3_b = (const float*)d_in[16];

    int n = in_sizes[0] / 3;
    int e = in_sizes[1] / 2;
    int nbuck = cdiv(n, 128);

    auto align256 = [](size_t x) { return (x + 255) & ~(size_t)255; };
    char* w = (char*)d_ws;
    int*    blockHist = (int*)w;    w += align256((size_t)BPART * NBINS * 4);
    int*    blockOff  = (int*)w;    w += align256((size_t)BPART * NBINS * 4);
    int*    bucketSt  = (int*)w;    w += align256((NBINS + 1) * 4);
    int*    rowptr    = (int*)w;    w += align256((size_t)(n + 1) * 4);
    int*    deg       = (int*)w;    w += align256((size_t)n * 4);
    int*    ebuf      = (int*)w;    w += align256((size_t)e * 4);
    float4* za        = (float4*)w; w += align256((size_t)n * 16);
    float4* zb        = (float4*)w; w += align256((size_t)n * 16);
    double* stats     = (double*)w; w += align256(9 * sizeof(double));
    int*    starts    = (int*)w;    w += align256((GG + 1) * 4);
    float*  pooled    = (float*)w;  w += align256((size_t)GG * HID * 4);
    float*  h1        = (float*)w;  w += align256((size_t)GG * H1 * 4);
    float*  h2        = (float*)w;  w += align256((size_t)GG * H2 * 4);

    (void)hipMemsetAsync(stats, 0, 9 * sizeof(double), stream);

    const int* erow = ei;
    const int* ecol = ei + e;

    k_hista<<<BPART, 1024, 0, stream>>>(ecol, blockHist, e);
    k_scan <<<1, NBINS, 0, stream>>>(blockHist, blockOff, bucketSt, rowptr, e, n);
    k_scat <<<BPART, 1024, 0, stream>>>(erow, ecol, blockOff, bucketSt, ebuf, e);
    k_csr  <<<nbuck, 256, 0, stream>>>(bucketSt, ebuf, rowptr, deg, pos, za, n);

    int gn = cdiv(n, 256);
    // K=5 passes, double-buffered: za->zb->za->zb->za->zb (final in zb)
    k_gather<false><<<gn, 256, 0, stream>>>(ebuf, rowptr, za, zb, stats, n);
    k_gather<false><<<gn, 256, 0, stream>>>(ebuf, rowptr, zb, za, stats, n);
    k_gather<false><<<gn, 256, 0, stream>>>(ebuf, rowptr, za, zb, stats, n);
    k_gather<false><<<gn, 256, 0, stream>>>(ebuf, rowptr, zb, za, stats, n);
    k_gather<true ><<<gn, 256, 0, stream>>>(ebuf, rowptr, za, zb, stats, n);

    k_bounds<<<1, 128, 0, stream>>>(batch, starts, n);
    k_pool<<<dim3(GG, HID / 256), 256, 0, stream>>>(zb, starts, lin_w, bn0_g, bn0_b, stats, pooled, n);
    k_fcbn<HID><<<H1, 64, 0, stream>>>(pooled, fc1_w, fc1_b, bn1_g, bn1_b, h1, H1);
    k_fcbn<H1><<<H2, 64, 0, stream>>>(h1, fc2_w, fc2_b, bn2_g, bn2_b, h2, H2);
    k_out<<<GG, 64, 0, stream>>>(h2, fc3_w, fc3_b, (float*)d_out);
}